// Round 1
// baseline (258.799 us; speedup 1.0000x reference)
//
#include <hip/hip_runtime.h>

typedef __bf16 bf16x8 __attribute__((ext_vector_type(8)));
typedef float  f32x4  __attribute__((ext_vector_type(4)));

#define AS1 __attribute__((address_space(1)))
#define AS3 __attribute__((address_space(3)))

__device__ __forceinline__ float bf2f(ushort u) {
    union { unsigned int i; float f; } v; v.i = ((unsigned int)u) << 16; return v.f;
}
__device__ __forceinline__ ushort f2bf(float f) {
    union { float f; unsigned int i; } v; v.f = f;
    unsigned int i = v.i;
    unsigned int r = i + 0x7FFFu + ((i >> 16) & 1u);   // RNE
    return (ushort)(r >> 16);
}
__device__ __forceinline__ float bflo(unsigned int u) { return bf2f((ushort)(u & 0xFFFFu)); }
__device__ __forceinline__ float bfhi(unsigned int u) { return bf2f((ushort)(u >> 16)); }
__device__ __forceinline__ float gelu_f(float v) {
    return 0.5f * v * (1.f + erff(v * 0.70710678118654752f));
}

// wave-level inline dtype sniff: 1 = bf16 inputs, 0 = f32
__device__ __forceinline__ bool sniff_inline(const ushort* __restrict__ x) {
    const int lane = threadIdx.x & 63;
    int cnt = 0;
    #pragma unroll
    for (int r = 0; r < 4; r++) {
        const ushort u = x[lane + r * 64];
        const int e = (u >> 7) & 0xFF;
        if ((u & 0x7FFF) == 0 || (e >= 112 && e <= 141)) cnt++;
    }
    #pragma unroll
    for (int o = 32; o > 0; o >>= 1) cnt += __shfl_xor(cnt, o);
    return cnt >= 224;
}

// ---------------------------------------------------------------------------
// canonicalize all inputs into packed bf16 region; also writes xpw_pad [64,512]
// ---------------------------------------------------------------------------
struct CanonArgs {
    const void* src[20];
    int off[20];
    int total;
};

__launch_bounds__(256)
__global__ void canon_k(CanonArgs a, ushort* __restrict__ dst, ushort* __restrict__ xpw_pad,
                        const ushort* __restrict__ sniffx)
{
    const int i = blockIdx.x * 256 + threadIdx.x;
    if (i >= a.total) {
        const int j = i - a.total;
        if (j < 8192) xpw_pad[24576 + j] = 0;   // pad rows 48..63
        return;
    }
    const bool fl = sniff_inline(sniffx);
    int s = 0;
    #pragma unroll
    for (int t = 1; t < 20; t++) if (i >= a.off[t]) s = t;
    const int li = i - a.off[s];
    ushort v;
    if (fl) v = ((const ushort*)a.src[s])[li];
    else    v = f2bf(((const float*)a.src[s])[li]);
    dst[i] = v;
    if (s == 5) xpw_pad[li] = v;                // xpw rows 0..47
}

// ---------------------------------------------------------------------------
// in_proj GEMM: xz[8192,1024] = x @ ipw^T + ipb
// ---------------------------------------------------------------------------
template<int BM, int BN>
__launch_bounds__(256, 2)
__global__ void gemm_bt(const ushort* __restrict__ A, const ushort* __restrict__ W,
                        const ushort* __restrict__ bias, ushort* __restrict__ Cb,
                        int N, int K)
{
    constexpr int WMT = BM / 32;
    constexpr int WNT = BN / 32;
    __shared__ __align__(16) ushort As[BM * 32];
    __shared__ __align__(16) ushort Bs[BN * 32];
    const int tid  = threadIdx.x;
    const int wave = tid >> 6;
    const int lane = tid & 63;
    const int m0 = blockIdx.x * BM;
    const int n0 = blockIdx.y * BN;
    const int wm = (wave >> 1) * (BM / 2);
    const int wn = (wave & 1) * (BN / 2);
    const int lrow = lane & 15;
    const int quad = lane >> 4;

    f32x4 acc[WMT][WNT];
    #pragma unroll
    for (int i = 0; i < WMT; i++)
        #pragma unroll
        for (int j = 0; j < WNT; j++)
            #pragma unroll
            for (int r = 0; r < 4; r++) acc[i][j][r] = 0.f;

    for (int k0 = 0; k0 < K; k0 += 32) {
        #pragma unroll
        for (int t = 0; t < BM / 64; t++) {
            const int inst = t * 4 + wave;
            const int row  = inst * 16 + (lane >> 2);
            const int sub  = lane & 3;
            const ushort* gp = A + (size_t)(m0 + row) * K + (k0 + sub * 8);
            __builtin_amdgcn_global_load_lds((AS1 void*)(void*)gp,
                                             (AS3 void*)(As + inst * 512), 16, 0, 0);
        }
        #pragma unroll
        for (int t = 0; t < BN / 64; t++) {
            const int inst = t * 4 + wave;
            const int row  = inst * 16 + (lane >> 2);
            const int sub  = lane & 3;
            const ushort* gp = W + (size_t)(n0 + row) * K + (k0 + sub * 8);
            __builtin_amdgcn_global_load_lds((AS1 void*)(void*)gp,
                                             (AS3 void*)(Bs + inst * 512), 16, 0, 0);
        }
        __syncthreads();
        bf16x8 afr[WMT], bfr[WNT];
        #pragma unroll
        for (int i = 0; i < WMT; i++)
            afr[i] = *(const bf16x8*)&As[(wm + i * 16 + lrow) * 32 + quad * 8];
        #pragma unroll
        for (int j = 0; j < WNT; j++)
            bfr[j] = *(const bf16x8*)&Bs[(wn + j * 16 + lrow) * 32 + quad * 8];
        #pragma unroll
        for (int i = 0; i < WMT; i++)
            #pragma unroll
            for (int j = 0; j < WNT; j++)
                acc[i][j] = __builtin_amdgcn_mfma_f32_16x16x32_bf16(afr[i], bfr[j], acc[i][j], 0, 0, 0);
        __syncthreads();
    }

    #pragma unroll
    for (int i = 0; i < WMT; i++) {
        const int gm = m0 + wm + i * 16 + quad * 4;
        #pragma unroll
        for (int j = 0; j < WNT; j++) {
            const int gn = n0 + wn + j * 16 + lrow;
            const float bv = bf2f(bias[gn]);
            #pragma unroll
            for (int r = 0; r < 4; r++)
                Cb[(size_t)(gm + r) * N + gn] = f2bf(acc[i][j][r] + bv);
        }
    }
}

// ---------------------------------------------------------------------------
// conv+SiLU (16 tokens, LDS) -> xdbl GEMM (LDS A, prefetched L2 B) -> scan1
// chunk = 16 tokens; grid (128 c, 4 b) x 512 threads -> 2 blocks/CU
// scan1 stores local h[16] (summh) + scalar sum-dt (sdtb); decay factors are
// recomputed in combine_k (p = exp(A[n]*sdt)), halving state traffic.
// ---------------------------------------------------------------------------
__launch_bounds__(512)
__global__ void convscan1_k(const ushort* __restrict__ xz, const ushort* __restrict__ cw,
                            const ushort* __restrict__ cb, const ushort* __restrict__ xpw_pad,
                            const ushort* __restrict__ dtw, const ushort* __restrict__ dtb,
                            const ushort* __restrict__ Alog,
                            float* __restrict__ xdbl, float* __restrict__ summh,
                            float* __restrict__ sdtb)
{
    __shared__ __align__(16) ushort xcs[16 * 520];
    __shared__ float XD[16 * 48];
    const int tid  = threadIdx.x;
    const int wave = tid >> 6;
    const int lane = tid & 63;
    const int lrow = lane & 15;
    const int quad = lane >> 4;
    const int c = blockIdx.x, b = blockIdx.y;
    const int t0 = b * 2048 + c * 16;

    // ---- conv + silu ----
    {
        const int d8 = (tid & 63) * 8;
        ushort wl[32];
        *(uint4*)&wl[0]  = *(const uint4*)&cw[d8 * 4];
        *(uint4*)&wl[8]  = *(const uint4*)&cw[d8 * 4 + 8];
        *(uint4*)&wl[16] = *(const uint4*)&cw[d8 * 4 + 16];
        *(uint4*)&wl[24] = *(const uint4*)&cw[d8 * 4 + 24];
        ushort bl[8];
        *(uint4*)&bl[0] = *(const uint4*)&cb[d8];
        #pragma unroll
        for (int it = 0; it < 2; it++) {
            const int trow = it * 8 + wave;
            const int t = t0 + trow;
            const int l = t & 2047;
            float acc[8];
            #pragma unroll
            for (int j = 0; j < 8; j++) acc[j] = bf2f(bl[j]);
            #pragma unroll
            for (int k = 0; k < 4; k++) {
                const int ls = l - 3 + k;
                if (ls >= 0) {
                    ushort xl[8];
                    *(uint4*)&xl[0] = *(const uint4*)&xz[(size_t)(t - 3 + k) * 1024 + d8];
                    #pragma unroll
                    for (int j = 0; j < 8; j++) acc[j] += bf2f(xl[j]) * bf2f(wl[j * 4 + k]);
                }
            }
            ushort ol[8];
            #pragma unroll
            for (int j = 0; j < 8; j++) {
                const float s = acc[j] / (1.f + __expf(-acc[j]));
                ol[j] = f2bf(s);
            }
            *(uint4*)&xcs[trow * 520 + d8] = *(uint4*)&ol[0];
        }
    }
    __syncthreads();

    // ---- xdbl = xcs @ xpw_pad^T: M=16, N=48(64 pad), K=512; waves 0..2 ----
    if (wave < 3) {
        const int nt = wave;
        const ushort* bptr = xpw_pad + (size_t)(nt * 16 + lrow) * 512 + quad * 8;
        f32x4 acc = {0.f, 0.f, 0.f, 0.f};
        bf16x8 bn = *(const bf16x8*)bptr;
        for (int k0 = 0; k0 < 512; k0 += 32) {
            const bf16x8 bc = bn;
            if (k0 + 32 < 512) bn = *(const bf16x8*)(bptr + k0 + 32);
            const bf16x8 afr = *(const bf16x8*)&xcs[lrow * 520 + k0 + quad * 8];
            acc = __builtin_amdgcn_mfma_f32_16x16x32_bf16(afr, bc, acc, 0, 0, 0);
        }
        const int col = nt * 16 + lrow;
        #pragma unroll
        for (int r = 0; r < 4; r++) {
            const int row = quad * 4 + r;
            XD[row * 48 + col] = acc[r];
            xdbl[(size_t)(t0 + row) * 64 + col] = acc[r];
        }
    }
    __syncthreads();

    // ---- scan pass 1: thread owns one d ----
    {
        const int d = tid;
        const uint4 w0 = *(const uint4*)&dtw[d * 16];
        const uint4 w1 = *(const uint4*)&dtw[d * 16 + 8];
        const float wd[16] = { bflo(w0.x), bfhi(w0.x), bflo(w0.y), bfhi(w0.y),
                               bflo(w0.z), bfhi(w0.z), bflo(w0.w), bfhi(w0.w),
                               bflo(w1.x), bfhi(w1.x), bflo(w1.y), bfhi(w1.y),
                               bflo(w1.z), bfhi(w1.z), bflo(w1.w), bfhi(w1.w) };
        const float dtbv = bf2f(dtb[d]);
        float A[16], h[16];
        #pragma unroll
        for (int n = 0; n < 16; n++) {
            A[n] = -__expf(bf2f(Alog[d * 16 + n]));
            h[n] = 0.f;
        }
        float sdt = 0.f;
        for (int i = 0; i < 16; i++) {
            const float* Xr = &XD[i * 48];
            float s = dtbv;
            #pragma unroll
            for (int k = 0; k < 16; k++) s += Xr[k] * wd[k];
            const float dtv = (s > 15.f) ? s : __logf(1.f + __expf(s));
            const float xiv = bf2f(xcs[i * 520 + d]);
            const float dx = dtv * xiv;
            sdt += dtv;
            #pragma unroll
            for (int n = 0; n < 16; n++) {
                const float da = __expf(dtv * A[n]);
                h[n] = da * h[n] + dx * Xr[16 + n];
            }
        }
        const size_t bh = ((size_t)(b * 128 + c) * 16) * 512 + d;
        #pragma unroll
        for (int n = 0; n < 16; n++) summh[bh + (size_t)n * 512] = h[n];
        sdtb[(size_t)(b * 128 + c) * 512 + d] = sdt;
    }
}

// sequential combine over 128 chunks, register-batched; recomputes decay
// p = exp(A[n]*sdt); overwrites h-slot with incoming state h_in
__launch_bounds__(512)
__global__ void combine_k(float* __restrict__ summh, const float* __restrict__ sdtb,
                          const ushort* __restrict__ Alog)
{
    const int b = blockIdx.x >> 4, n = blockIdx.x & 15;
    const int d = threadIdx.x;
    const float An = -__expf(bf2f(Alog[d * 16 + n]));
    float h = 0.f;
    #pragma unroll
    for (int q = 0; q < 4; q++) {
        float p[32], hl[32], ho[32];
        #pragma unroll
        for (int c2 = 0; c2 < 32; c2++) {
            const int cc = q * 32 + c2;
            hl[c2] = summh[((size_t)(b * 128 + cc) * 16 + n) * 512 + d];
            p[c2]  = __expf(An * sdtb[(size_t)(b * 128 + cc) * 512 + d]);
        }
        #pragma unroll
        for (int c2 = 0; c2 < 32; c2++) {
            ho[c2] = h;
            h = p[c2] * h + hl[c2];
        }
        #pragma unroll
        for (int c2 = 0; c2 < 32; c2++)
            summh[((size_t)(b * 128 + (q * 32 + c2)) * 16 + n) * 512 + d] = ho[c2];
    }
}

// ---------------------------------------------------------------------------
// tail (chunk = 16 tokens): conv -> scan2 (y into LDS) -> out_proj+LN1 ->
// 4x(fc1 -> fc2 partial) -> gelu+resid -> LN2 -> d_out.
// grid (128,4) x 512 -> 2 blocks/CU for latency hiding.
// ---------------------------------------------------------------------------
__launch_bounds__(512)
__global__ void tail_k(const ushort* __restrict__ xz, const ushort* __restrict__ cw,
                       const ushort* __restrict__ cb, const float* __restrict__ xdbl,
                       const ushort* __restrict__ dtw, const ushort* __restrict__ dtb,
                       const ushort* __restrict__ Alog, const float* __restrict__ summh,
                       const ushort* __restrict__ Dssm, const ushort* __restrict__ cx,
                       const ushort* __restrict__ opw, const ushort* __restrict__ opb,
                       const ushort* __restrict__ ln1g, const ushort* __restrict__ ln1b,
                       const ushort* __restrict__ f1w, const ushort* __restrict__ f1b,
                       const ushort* __restrict__ f2w, const ushort* __restrict__ f2b,
                       const ushort* __restrict__ ln2g, const ushort* __restrict__ ln2b,
                       void* __restrict__ dout, const ushort* __restrict__ sniffx)
{
    __shared__ __align__(16) ushort yls[16 * 520];   // xi -> y (in place); later f1q
    __shared__ float XD[16 * 48];
    __shared__ __align__(16) ushort y1bs[16 * 264];
    __shared__ float redS[8 * 16], redQ[8 * 16];
    ushort* f1q = yls;                                // alias (stride 260, y dead)

    const int tid  = threadIdx.x;
    const int wave = tid >> 6;
    const int lane = tid & 63;
    const int lrow = lane & 15;
    const int quad = lane >> 4;
    const int c = blockIdx.x, b = blockIdx.y;
    const int t0 = b * 2048 + c * 16;
    const int n0w = wave * 32;

    // ---- conv + silu ----
    {
        const int d8 = (tid & 63) * 8;
        ushort wl[32];
        *(uint4*)&wl[0]  = *(const uint4*)&cw[d8 * 4];
        *(uint4*)&wl[8]  = *(const uint4*)&cw[d8 * 4 + 8];
        *(uint4*)&wl[16] = *(const uint4*)&cw[d8 * 4 + 16];
        *(uint4*)&wl[24] = *(const uint4*)&cw[d8 * 4 + 24];
        ushort bl[8];
        *(uint4*)&bl[0] = *(const uint4*)&cb[d8];
        #pragma unroll
        for (int it = 0; it < 2; it++) {
            const int trow = it * 8 + wave;
            const int t = t0 + trow;
            const int l = t & 2047;
            float acc[8];
            #pragma unroll
            for (int j = 0; j < 8; j++) acc[j] = bf2f(bl[j]);
            #pragma unroll
            for (int k = 0; k < 4; k++) {
                const int ls = l - 3 + k;
                if (ls >= 0) {
                    ushort xl[8];
                    *(uint4*)&xl[0] = *(const uint4*)&xz[(size_t)(t - 3 + k) * 1024 + d8];
                    #pragma unroll
                    for (int j = 0; j < 8; j++) acc[j] += bf2f(xl[j]) * bf2f(wl[j * 4 + k]);
                }
            }
            ushort ol[8];
            #pragma unroll
            for (int j = 0; j < 8; j++) {
                const float s = acc[j] / (1.f + __expf(-acc[j]));
                ol[j] = f2bf(s);
            }
            *(uint4*)&yls[trow * 520 + d8] = *(uint4*)&ol[0];
        }
    }
    for (int e = tid; e < 768; e += 512)
        XD[e] = xdbl[(size_t)(t0 + (e / 48)) * 64 + (e % 48)];
    __syncthreads();

    // ---- scan pass 2: thread owns one d; y overwrites xi in LDS ----
    {
        const int d = tid;
        const uint4 w0 = *(const uint4*)&dtw[d * 16];
        const uint4 w1 = *(const uint4*)&dtw[d * 16 + 8];
        const float wd[16] = { bflo(w0.x), bfhi(w0.x), bflo(w0.y), bfhi(w0.y),
                               bflo(w0.z), bfhi(w0.z), bflo(w0.w), bfhi(w0.w),
                               bflo(w1.x), bfhi(w1.x), bflo(w1.y), bfhi(w1.y),
                               bflo(w1.z), bfhi(w1.z), bflo(w1.w), bfhi(w1.w) };
        const float dtbv = bf2f(dtb[d]);
        float A[16], h[16];
        #pragma unroll
        for (int n = 0; n < 16; n++) A[n] = -__expf(bf2f(Alog[d * 16 + n]));
        const size_t bh = ((size_t)(b * 128 + c) * 16) * 512 + d;
        #pragma unroll
        for (int n = 0; n < 16; n++) h[n] = summh[bh + (size_t)n * 512];
        const float Dv = bf2f(Dssm[d]);
        for (int i = 0; i < 16; i++) {
            const int t = t0 + i;
            const float* Xr = &XD[i * 48];
            float s = dtbv;
            #pragma unroll
            for (int k = 0; k < 16; k++) s += Xr[k] * wd[k];
            const float dtv = (s > 15.f) ? s : __logf(1.f + __expf(s));
            const float xiv = bf2f(yls[i * 520 + d]);
            const float dx = dtv * xiv;
            float yv = 0.f;
            #pragma unroll
            for (int n = 0; n < 16; n++) {
                const float da = __expf(dtv * A[n]);
                h[n] = da * h[n] + dx * Xr[16 + n];
                yv += h[n] * Xr[32 + n];
            }
            yv += xiv * Dv;
            const float zv = bf2f(xz[(size_t)t * 1024 + 512 + d]);
            yv *= zv / (1.f + __expf(-zv));
            yls[i * 520 + d] = f2bf(yv);   // in-place (same thread, same slot)
        }
    }
    __syncthreads();

    // ---- out_proj: M=16, N=256, K=512 from LDS y; B prefetched ----
    f32x4 accP[2];
    #pragma unroll
    for (int j = 0; j < 2; j++)
        #pragma unroll
        for (int r = 0; r < 4; r++) accP[j][r] = 0.f;
    {
        const ushort* bp0 = opw + (size_t)(n0w + lrow) * 512 + quad * 8;
        const ushort* bp1 = opw + (size_t)(n0w + 16 + lrow) * 512 + quad * 8;
        bf16x8 bn0 = *(const bf16x8*)bp0;
        bf16x8 bn1 = *(const bf16x8*)bp1;
        for (int k0 = 0; k0 < 512; k0 += 32) {
            const bf16x8 bc0 = bn0, bc1 = bn1;
            if (k0 + 32 < 512) {
                bn0 = *(const bf16x8*)(bp0 + k0 + 32);
                bn1 = *(const bf16x8*)(bp1 + k0 + 32);
            }
            const bf16x8 afr = *(const bf16x8*)&yls[lrow * 520 + k0 + quad * 8];
            accP[0] = __builtin_amdgcn_mfma_f32_16x16x32_bf16(afr, bc0, accP[0], 0, 0, 0);
            accP[1] = __builtin_amdgcn_mfma_f32_16x16x32_bf16(afr, bc1, accP[1], 0, 0, 0);
        }
    }
    // epilogue + LN1 partials
    float vP[2][4];
    float ps[4], pq[4];
    #pragma unroll
    for (int r = 0; r < 4; r++) { ps[r] = 0.f; pq[r] = 0.f; }
    #pragma unroll
    for (int j = 0; j < 2; j++) {
        const int col = n0w + j * 16 + lrow;
        const float bv = bf2f(opb[col]);
        #pragma unroll
        for (int r = 0; r < 4; r++) {
            const int row = quad * 4 + r;
            float v = accP[j][r] + bv + bf2f(cx[(size_t)(t0 + row) * 256 + col]);
            vP[j][r] = v;
            ps[r] += v;
            pq[r] += v * v;
        }
    }
    #pragma unroll
    for (int r = 0; r < 4; r++) {
        #pragma unroll
        for (int o = 8; o > 0; o >>= 1) {
            ps[r] += __shfl_xor(ps[r], o);
            pq[r] += __shfl_xor(pq[r], o);
        }
        if (lrow == 0) {
            const int row = quad * 4 + r;
            redS[wave * 16 + row] = ps[r];
            redQ[wave * 16 + row] = pq[r];
        }
    }
    __syncthreads();

    // LN1 -> y1bs (bf16) + y1f in registers
    float y1f[2][4];
    #pragma unroll
    for (int r = 0; r < 4; r++) {
        const int row = quad * 4 + r;
        float S = 0.f, Q = 0.f;
        #pragma unroll
        for (int w = 0; w < 8; w++) { S += redS[w * 16 + row]; Q += redQ[w * 16 + row]; }
        const float mean = S * (1.f / 256.f);
        const float var  = Q * (1.f / 256.f) - mean * mean;
        const float rs   = rsqrtf(var + 1e-5f);
        #pragma unroll
        for (int j = 0; j < 2; j++) {
            const int col = n0w + j * 16 + lrow;
            const float o2 = (vP[j][r] - mean) * rs * bf2f(ln1g[col]) + bf2f(ln1b[col]);
            y1f[j][r] = o2;
            y1bs[row * 264 + col] = f2bf(o2);
        }
    }
    __syncthreads();

    // ---- fc1 (4 col-quarters) + fc2 partial-K accumulate; B prefetched ----
    f32x4 acc2[2];
    #pragma unroll
    for (int j = 0; j < 2; j++)
        #pragma unroll
        for (int r = 0; r < 4; r++) acc2[j][r] = 0.f;

    for (int q = 0; q < 4; q++) {
        f32x4 a1[2];
        #pragma unroll
        for (int j = 0; j < 2; j++)
            #pragma unroll
            for (int r = 0; r < 4; r++) a1[j][r] = 0.f;
        {
            const ushort* bp0 = f1w + (size_t)(q * 256 + n0w + lrow) * 256 + quad * 8;
            const ushort* bp1 = f1w + (size_t)(q * 256 + n0w + 16 + lrow) * 256 + quad * 8;
            bf16x8 bn0 = *(const bf16x8*)bp0;
            bf16x8 bn1 = *(const bf16x8*)bp1;
            for (int k0 = 0; k0 < 256; k0 += 32) {
                const bf16x8 bc0 = bn0, bc1 = bn1;
                if (k0 + 32 < 256) {
                    bn0 = *(const bf16x8*)(bp0 + k0 + 32);
                    bn1 = *(const bf16x8*)(bp1 + k0 + 32);
                }
                const bf16x8 afr = *(const bf16x8*)&y1bs[lrow * 264 + k0 + quad * 8];
                a1[0] = __builtin_amdgcn_mfma_f32_16x16x32_bf16(afr, bc0, a1[0], 0, 0, 0);
                a1[1] = __builtin_amdgcn_mfma_f32_16x16x32_bf16(afr, bc1, a1[1], 0, 0, 0);
            }
        }
        #pragma unroll
        for (int j = 0; j < 2; j++) {
            const int qc = n0w + j * 16 + lrow;
            const float bv = bf2f(f1b[q * 256 + qc]);
            #pragma unroll
            for (int r = 0; r < 4; r++) {
                const int row = quad * 4 + r;
                f1q[row * 260 + qc] = f2bf(gelu_f(a1[j][r] + bv));
            }
        }
        __syncthreads();
        {
            const ushort* bp0 = f2w + (size_t)(n0w + lrow) * 1024 + q * 256 + quad * 8;
            const ushort* bp1 = f2w + (size_t)(n0w + 16 + lrow) * 1024 + q * 256 + quad * 8;
            bf16x8 bn0 = *(const bf16x8*)bp0;
            bf16x8 bn1 = *(const bf16x8*)bp1;
            for (int k0 = 0; k0 < 256; k0 += 32) {
                const bf16x8 bc0 = bn0, bc1 = bn1;
                if (k0 + 32 < 256) {
                    bn0 = *(const bf16x8*)(bp0 + k0 + 32);
                    bn1 = *(const bf16x8*)(bp1 + k0 + 32);
                }
                const bf16x8 afr = *(const bf16x8*)&f1q[lrow * 260 + k0 + quad * 8];
                acc2[0] = __builtin_amdgcn_mfma_f32_16x16x32_bf16(afr, bc0, acc2[0], 0, 0, 0);
                acc2[1] = __builtin_amdgcn_mfma_f32_16x16x32_bf16(afr, bc1, acc2[1], 0, 0, 0);
            }
        }
        __syncthreads();
    }

    // ---- fc2 epilogue: gelu + resid y1f, LN2, write d_out ----
    float v2[2][4];
    #pragma unroll
    for (int r = 0; r < 4; r++) { ps[r] = 0.f; pq[r] = 0.f; }
    #pragma unroll
    for (int j = 0; j < 2; j++) {
        const int col = n0w + j * 16 + lrow;
        const float bv = bf2f(f2b[col]);
        #pragma unroll
        for (int r = 0; r < 4; r++) {
            const float v = gelu_f(acc2[j][r] + bv) + y1f[j][r];
            v2[j][r] = v;
            ps[r] += v;
            pq[r] += v * v;
        }
    }
    #pragma unroll
    for (int r = 0; r < 4; r++) {
        #pragma unroll
        for (int o = 8; o > 0; o >>= 1) {
            ps[r] += __shfl_xor(ps[r], o);
            pq[r] += __shfl_xor(pq[r], o);
        }
        if (lrow == 0) {
            const int row = quad * 4 + r;
            redS[wave * 16 + row] = ps[r];
            redQ[wave * 16 + row] = pq[r];
        }
    }
    __syncthreads();

    const bool fl = sniff_inline(sniffx);
    #pragma unroll
    for (int r = 0; r < 4; r++) {
        const int row = quad * 4 + r;
        float S = 0.f, Q = 0.f;
        #pragma unroll
        for (int w = 0; w < 8; w++) { S += redS[w * 16 + row]; Q += redQ[w * 16 + row]; }
        const float mean = S * (1.f / 256.f);
        const float var  = Q * (1.f / 256.f) - mean * mean;
        const float rs   = rsqrtf(var + 1e-5f);
        #pragma unroll
        for (int j = 0; j < 2; j++) {
            const int col = n0w + j * 16 + lrow;
            const size_t off = (size_t)(t0 + row) * 256 + col;
            const float o2 = (v2[j][r] - mean) * rs * bf2f(ln2g[col]) + bf2f(ln2b[col]);
            if (fl) ((ushort*)dout)[off] = f2bf(o2);
            else    ((float*)dout)[off]  = o2;
        }
    }
}

// ---------------------------------------------------------------------------
extern "C" void kernel_launch(void* const* d_in, const int* in_sizes, int n_in,
                              void* d_out, int out_size, void* d_ws, size_t ws_size,
                              hipStream_t stream)
{
    char* ws = (char*)d_ws;
    ushort* canon = (ushort*)(ws + 256);

    static const int coff[20] = {
        0,        2097152,  2359296,  2360320,  2362368,
        2362880,  2387456,  2395648,  2396160,  2404352,
        2404864,  2535936,  2536192,  2536448,  2536704,
        2798848,  2799872,  3062016,  3062272,  3062528 };
    static const int ctot = 3062784;

    CanonArgs ca;
    for (int i = 0; i < 20; i++) { ca.src[i] = d_in[i]; ca.off[i] = coff[i]; }
    ca.total = ctot;

    const ushort* cx   = canon + coff[0];
    const ushort* cipw = canon + coff[1];
    const ushort* cipb = canon + coff[2];
    const ushort* ccw  = canon + coff[3];
    const ushort* ccb  = canon + coff[4];
    const ushort* cdtw = canon + coff[6];
    const ushort* cdtb = canon + coff[7];
    const ushort* calog= canon + coff[8];
    const ushort* cdssm= canon + coff[9];
    const ushort* copw = canon + coff[10];
    const ushort* copb = canon + coff[11];
    const ushort* cln1g= canon + coff[12];
    const ushort* cln1b= canon + coff[13];
    const ushort* cf1w = canon + coff[14];
    const ushort* cf1b = canon + coff[15];
    const ushort* cf2w = canon + coff[16];
    const ushort* cf2b = canon + coff[17];
    const ushort* cln2g= canon + coff[18];
    const ushort* cln2b= canon + coff[19];

    ushort* xpw_pad = (ushort*)(ws + 6291456);   // [64,512] bf16
    ushort* xz      = (ushort*)(ws + 8388608);   // [8192,1024] bf16, 16 MB
    float*  xdbl    = (float*)(ws + 25165824);   // [8192,64] f32, 2 MB
    float*  summh   = (float*)(ws + 27262976);   // [4,128,16,512] f32, 16 MB
    float*  sdtb    = (float*)(ws + 44040192);   // [4,128,512] f32, 1 MB
    const ushort* sx = (const ushort*)d_in[0];

    // 1. canon + xpw padding
    canon_k<<<(ctot + 8192 + 255) / 256, 256, 0, stream>>>(ca, canon, xpw_pad, sx);
    // 2. in_proj: xz = x @ ipw^T + ipb
    gemm_bt<128, 128><<<dim3(64, 8), 256, 0, stream>>>(cx, cipw, cipb, xz, 1024, 256);
    // 3. conv + silu + xdbl + scan1 (fused, 16-token chunks)
    convscan1_k<<<dim3(128, 4), 512, 0, stream>>>(
        xz, ccw, ccb, xpw_pad, cdtw, cdtb, calog, xdbl, summh, sdtb);
    // 4. combine (chunk-boundary states, decay recomputed from sdt)
    combine_k<<<64, 512, 0, stream>>>(summh, sdtb, calog);
    // 5. tail: scan2 + out_proj + LN1 + fc1 + fc2 + LN2 -> d_out
    tail_k<<<dim3(128, 4), 512, 0, stream>>>(
        xz, ccw, ccb, xdbl, cdtw, cdtb, calog, summh, cdssm, cx,
        copw, copb, cln1g, cln1b, cf1w, cf1b, cf2w, cf2b, cln2g, cln2b,
        d_out, sx);
}

// Round 3
// 255.452 us; speedup vs baseline: 1.0131x; 1.0131x over previous
//
#include <hip/hip_runtime.h>

typedef __bf16 bf16x8 __attribute__((ext_vector_type(8)));
typedef float  f32x4  __attribute__((ext_vector_type(4)));

#define AS1 __attribute__((address_space(1)))
#define AS3 __attribute__((address_space(3)))

__device__ __forceinline__ float bf2f(ushort u) {
    union { unsigned int i; float f; } v; v.i = ((unsigned int)u) << 16; return v.f;
}
__device__ __forceinline__ ushort f2bf(float f) {
    union { float f; unsigned int i; } v; v.f = f;
    unsigned int i = v.i;
    unsigned int r = i + 0x7FFFu + ((i >> 16) & 1u);   // RNE
    return (ushort)(r >> 16);
}
__device__ __forceinline__ float bflo(unsigned int u) { return bf2f((ushort)(u & 0xFFFFu)); }
__device__ __forceinline__ float bfhi(unsigned int u) { return bf2f((ushort)(u >> 16)); }
__device__ __forceinline__ float gelu_f(float v) {
    return 0.5f * v * (1.f + erff(v * 0.70710678118654752f));
}

// wave-level inline dtype sniff: 1 = bf16 inputs, 0 = f32
__device__ __forceinline__ bool sniff_inline(const ushort* __restrict__ x) {
    const int lane = threadIdx.x & 63;
    int cnt = 0;
    #pragma unroll
    for (int r = 0; r < 4; r++) {
        const ushort u = x[lane + r * 64];
        const int e = (u >> 7) & 0xFF;
        if ((u & 0x7FFF) == 0 || (e >= 112 && e <= 141)) cnt++;
    }
    #pragma unroll
    for (int o = 32; o > 0; o >>= 1) cnt += __shfl_xor(cnt, o);
    return cnt >= 224;
}

// ---------------------------------------------------------------------------
// canonicalize all inputs into packed bf16 region; also writes xpw_pad [64,512]
// ---------------------------------------------------------------------------
struct CanonArgs {
    const void* src[20];
    int off[20];
    int total;
};

__launch_bounds__(256)
__global__ void canon_k(CanonArgs a, ushort* __restrict__ dst, ushort* __restrict__ xpw_pad,
                        const ushort* __restrict__ sniffx)
{
    const int i = blockIdx.x * 256 + threadIdx.x;
    if (i >= a.total) {
        const int j = i - a.total;
        if (j < 8192) xpw_pad[24576 + j] = 0;   // pad rows 48..63
        return;
    }
    const bool fl = sniff_inline(sniffx);
    int s = 0;
    #pragma unroll
    for (int t = 1; t < 20; t++) if (i >= a.off[t]) s = t;
    const int li = i - a.off[s];
    ushort v;
    if (fl) v = ((const ushort*)a.src[s])[li];
    else    v = f2bf(((const float*)a.src[s])[li]);
    dst[i] = v;
    if (s == 5) xpw_pad[li] = v;                // xpw rows 0..47
}

// ---------------------------------------------------------------------------
// in_proj GEMM: xz[8192,1024] = x @ ipw^T + ipb
// ---------------------------------------------------------------------------
template<int BM, int BN>
__launch_bounds__(256, 2)
__global__ void gemm_bt(const ushort* __restrict__ A, const ushort* __restrict__ W,
                        const ushort* __restrict__ bias, ushort* __restrict__ Cb,
                        int N, int K)
{
    constexpr int WMT = BM / 32;
    constexpr int WNT = BN / 32;
    __shared__ __align__(16) ushort As[BM * 32];
    __shared__ __align__(16) ushort Bs[BN * 32];
    const int tid  = threadIdx.x;
    const int wave = tid >> 6;
    const int lane = tid & 63;
    const int m0 = blockIdx.x * BM;
    const int n0 = blockIdx.y * BN;
    const int wm = (wave >> 1) * (BM / 2);
    const int wn = (wave & 1) * (BN / 2);
    const int lrow = lane & 15;
    const int quad = lane >> 4;

    f32x4 acc[WMT][WNT];
    #pragma unroll
    for (int i = 0; i < WMT; i++)
        #pragma unroll
        for (int j = 0; j < WNT; j++)
            #pragma unroll
            for (int r = 0; r < 4; r++) acc[i][j][r] = 0.f;

    for (int k0 = 0; k0 < K; k0 += 32) {
        #pragma unroll
        for (int t = 0; t < BM / 64; t++) {
            const int inst = t * 4 + wave;
            const int row  = inst * 16 + (lane >> 2);
            const int sub  = lane & 3;
            const ushort* gp = A + (size_t)(m0 + row) * K + (k0 + sub * 8);
            __builtin_amdgcn_global_load_lds((AS1 void*)(void*)gp,
                                             (AS3 void*)(As + inst * 512), 16, 0, 0);
        }
        #pragma unroll
        for (int t = 0; t < BN / 64; t++) {
            const int inst = t * 4 + wave;
            const int row  = inst * 16 + (lane >> 2);
            const int sub  = lane & 3;
            const ushort* gp = W + (size_t)(n0 + row) * K + (k0 + sub * 8);
            __builtin_amdgcn_global_load_lds((AS1 void*)(void*)gp,
                                             (AS3 void*)(Bs + inst * 512), 16, 0, 0);
        }
        __syncthreads();
        bf16x8 afr[WMT], bfr[WNT];
        #pragma unroll
        for (int i = 0; i < WMT; i++)
            afr[i] = *(const bf16x8*)&As[(wm + i * 16 + lrow) * 32 + quad * 8];
        #pragma unroll
        for (int j = 0; j < WNT; j++)
            bfr[j] = *(const bf16x8*)&Bs[(wn + j * 16 + lrow) * 32 + quad * 8];
        #pragma unroll
        for (int i = 0; i < WMT; i++)
            #pragma unroll
            for (int j = 0; j < WNT; j++)
                acc[i][j] = __builtin_amdgcn_mfma_f32_16x16x32_bf16(afr[i], bfr[j], acc[i][j], 0, 0, 0);
        __syncthreads();
    }

    #pragma unroll
    for (int i = 0; i < WMT; i++) {
        const int gm = m0 + wm + i * 16 + quad * 4;
        #pragma unroll
        for (int j = 0; j < WNT; j++) {
            const int gn = n0 + wn + j * 16 + lrow;
            const float bv = bf2f(bias[gn]);
            #pragma unroll
            for (int r = 0; r < 4; r++)
                Cb[(size_t)(gm + r) * N + gn] = f2bf(acc[i][j][r] + bv);
        }
    }
}

// ---------------------------------------------------------------------------
// conv+SiLU (32 tokens, LDS) -> xdbl GEMM (deep B prefetch) -> scan1
// chunk = 32 tokens; grid (64 c, 4 b) x 512 threads
// stores h/sdt at BOTH 16-token midpoint (hhalf/sdthalf) and chunk end
// (summh/sdt32) so tail can run at 16-token granularity.
// ---------------------------------------------------------------------------
__launch_bounds__(512)
__global__ void convscan1_k(const ushort* __restrict__ xz, const ushort* __restrict__ cw,
                            const ushort* __restrict__ cb, const ushort* __restrict__ xpw_pad,
                            const ushort* __restrict__ dtw, const ushort* __restrict__ dtb,
                            const ushort* __restrict__ Alog,
                            float* __restrict__ xdbl, float* __restrict__ summh,
                            float* __restrict__ sdt32, float* __restrict__ hhalf,
                            float* __restrict__ sdthalf)
{
    __shared__ __align__(16) ushort xcs[32 * 520];
    __shared__ float XD[32 * 48];
    const int tid  = threadIdx.x;
    const int wave = tid >> 6;
    const int lane = tid & 63;
    const int lrow = lane & 15;
    const int quad = lane >> 4;
    const int c = blockIdx.x, b = blockIdx.y;
    const int t0 = b * 2048 + c * 32;

    // ---- conv + silu ----
    {
        const int d8 = (tid & 63) * 8;
        ushort wl[32];
        *(uint4*)&wl[0]  = *(const uint4*)&cw[d8 * 4];
        *(uint4*)&wl[8]  = *(const uint4*)&cw[d8 * 4 + 8];
        *(uint4*)&wl[16] = *(const uint4*)&cw[d8 * 4 + 16];
        *(uint4*)&wl[24] = *(const uint4*)&cw[d8 * 4 + 24];
        ushort bl[8];
        *(uint4*)&bl[0] = *(const uint4*)&cb[d8];
        #pragma unroll
        for (int it = 0; it < 4; it++) {
            const int trow = it * 8 + wave;
            const int t = t0 + trow;
            const int l = t & 2047;
            float acc[8];
            #pragma unroll
            for (int j = 0; j < 8; j++) acc[j] = bf2f(bl[j]);
            #pragma unroll
            for (int k = 0; k < 4; k++) {
                const int ls = l - 3 + k;
                if (ls >= 0) {
                    ushort xl[8];
                    *(uint4*)&xl[0] = *(const uint4*)&xz[(size_t)(t - 3 + k) * 1024 + d8];
                    #pragma unroll
                    for (int j = 0; j < 8; j++) acc[j] += bf2f(xl[j]) * bf2f(wl[j * 4 + k]);
                }
            }
            ushort ol[8];
            #pragma unroll
            for (int j = 0; j < 8; j++) {
                const float s = acc[j] / (1.f + __expf(-acc[j]));
                ol[j] = f2bf(s);
            }
            *(uint4*)&xcs[trow * 520 + d8] = *(uint4*)&ol[0];
        }
    }
    __syncthreads();

    // ---- xdbl = xcs @ xpw_pad^T: M=32, N=48(64 pad), K=512; 8 waves ----
    {
        const int mt = wave >> 2, nt = wave & 3;
        const ushort* bptr = xpw_pad + (size_t)(nt * 16 + lrow) * 512 + quad * 8;
        f32x4 acc = {0.f, 0.f, 0.f, 0.f};
        #pragma unroll
        for (int hh = 0; hh < 2; hh++) {
            bf16x8 Bv[8];
            #pragma unroll
            for (int s = 0; s < 8; s++)
                Bv[s] = *(const bf16x8*)(bptr + hh * 256 + s * 32);
            #pragma unroll
            for (int s = 0; s < 8; s++) {
                const bf16x8 afr = *(const bf16x8*)&xcs[(mt * 16 + lrow) * 520 + hh * 256 + s * 32 + quad * 8];
                acc = __builtin_amdgcn_mfma_f32_16x16x32_bf16(afr, Bv[s], acc, 0, 0, 0);
            }
        }
        const int col = nt * 16 + lrow;
        if (col < 48) {
            #pragma unroll
            for (int r = 0; r < 4; r++) {
                const int row = mt * 16 + quad * 4 + r;
                XD[row * 48 + col] = acc[r];
                xdbl[(size_t)(t0 + row) * 64 + col] = acc[r];
            }
        }
    }
    __syncthreads();

    // ---- scan pass 1: thread owns one d ----
    {
        const int d = tid;
        const uint4 w0 = *(const uint4*)&dtw[d * 16];
        const uint4 w1 = *(const uint4*)&dtw[d * 16 + 8];
        const float wd[16] = { bflo(w0.x), bfhi(w0.x), bflo(w0.y), bfhi(w0.y),
                               bflo(w0.z), bfhi(w0.z), bflo(w0.w), bfhi(w0.w),
                               bflo(w1.x), bfhi(w1.x), bflo(w1.y), bfhi(w1.y),
                               bflo(w1.z), bfhi(w1.z), bflo(w1.w), bfhi(w1.w) };
        const float dtbv = bf2f(dtb[d]);
        float A[16], h[16];
        #pragma unroll
        for (int n = 0; n < 16; n++) {
            A[n] = -__expf(bf2f(Alog[d * 16 + n]));
            h[n] = 0.f;
        }
        const size_t bh = ((size_t)(b * 64 + c) * 16) * 512 + d;
        const size_t bs = (size_t)(b * 64 + c) * 512 + d;
        float sdt = 0.f;
        for (int i = 0; i < 32; i++) {
            const float* Xr = &XD[i * 48];
            float s0 = dtbv, s1 = 0.f, s2 = 0.f, s3 = 0.f;
            #pragma unroll
            for (int k = 0; k < 16; k += 4) {
                s0 += Xr[k]     * wd[k];
                s1 += Xr[k + 1] * wd[k + 1];
                s2 += Xr[k + 2] * wd[k + 2];
                s3 += Xr[k + 3] * wd[k + 3];
            }
            const float s = (s0 + s1) + (s2 + s3);
            const float dtv = (s > 15.f) ? s : __logf(1.f + __expf(s));
            const float xiv = bf2f(xcs[i * 520 + d]);
            const float dx = dtv * xiv;
            sdt += dtv;
            #pragma unroll
            for (int n = 0; n < 16; n++) {
                const float da = __expf(dtv * A[n]);
                h[n] = da * h[n] + dx * Xr[16 + n];
            }
            if (i == 15) {
                #pragma unroll
                for (int n = 0; n < 16; n++) hhalf[bh + (size_t)n * 512] = h[n];
                sdthalf[bs] = sdt;
            }
        }
        #pragma unroll
        for (int n = 0; n < 16; n++) summh[bh + (size_t)n * 512] = h[n];
        sdt32[bs] = sdt;
    }
}

// sequential combine over 64 chunks, register-batched; recomputes decay
// p = exp(A[n]*sdt32); overwrites h-slot with incoming state h_in.
// grid 256 blocks x 128 threads (b,n,d-quarter) -> all CUs participate.
__launch_bounds__(128)
__global__ void combine_k(float* __restrict__ summh, const float* __restrict__ sdt32,
                          const ushort* __restrict__ Alog)
{
    const int b  = blockIdx.x >> 6;
    const int n  = (blockIdx.x >> 2) & 15;
    const int dq = blockIdx.x & 3;
    const int d  = dq * 128 + threadIdx.x;
    const float An = -__expf(bf2f(Alog[d * 16 + n]));
    float h = 0.f;
    #pragma unroll
    for (int q = 0; q < 2; q++) {
        float p[32], hl[32], ho[32];
        #pragma unroll
        for (int c2 = 0; c2 < 32; c2++) {
            const int cc = q * 32 + c2;
            hl[c2] = summh[((size_t)(b * 64 + cc) * 16 + n) * 512 + d];
            p[c2]  = __expf(An * sdt32[(size_t)(b * 64 + cc) * 512 + d]);
        }
        #pragma unroll
        for (int c2 = 0; c2 < 32; c2++) {
            ho[c2] = h;
            h = p[c2] * h + hl[c2];
        }
        #pragma unroll
        for (int c2 = 0; c2 < 32; c2++)
            summh[((size_t)(b * 64 + (q * 32 + c2)) * 16 + n) * 512 + d] = ho[c2];
    }
}

// ---------------------------------------------------------------------------
// tail (chunk = 16 tokens): conv -> scan2 (h_in bridged from 32-chunk state)
// -> out_proj+LN1 -> 4x(fc1 -> fc2 partial) -> gelu+resid -> LN2 -> d_out.
// grid (128,4) x 512 -> 2 blocks/CU. GEMM B-operands batch-preloaded
// (8 k-steps deep) to hide L2 latency; VGPR capped at 128 via launch_bounds.
// ---------------------------------------------------------------------------
__launch_bounds__(512, 4)
__global__ void tail_k(const ushort* __restrict__ xz, const ushort* __restrict__ cw,
                       const ushort* __restrict__ cb, const float* __restrict__ xdbl,
                       const ushort* __restrict__ dtw, const ushort* __restrict__ dtb,
                       const ushort* __restrict__ Alog, const float* __restrict__ summh,
                       const float* __restrict__ hhalf, const float* __restrict__ sdthalf,
                       const ushort* __restrict__ Dssm, const ushort* __restrict__ cx,
                       const ushort* __restrict__ opw, const ushort* __restrict__ opb,
                       const ushort* __restrict__ ln1g, const ushort* __restrict__ ln1b,
                       const ushort* __restrict__ f1w, const ushort* __restrict__ f1b,
                       const ushort* __restrict__ f2w, const ushort* __restrict__ f2b,
                       const ushort* __restrict__ ln2g, const ushort* __restrict__ ln2b,
                       void* __restrict__ dout, const ushort* __restrict__ sniffx)
{
    __shared__ __align__(16) ushort yls[16 * 520];   // xi -> y (in place); later f1q
    __shared__ float XD[16 * 48];
    __shared__ __align__(16) ushort y1bs[16 * 264];
    __shared__ float redS[8 * 16], redQ[8 * 16];
    ushort* f1q = yls;                                // alias (stride 260, y dead)

    const int tid  = threadIdx.x;
    const int wave = tid >> 6;
    const int lane = tid & 63;
    const int lrow = lane & 15;
    const int quad = lane >> 4;
    const int c = blockIdx.x, b = blockIdx.y;
    const int t0 = b * 2048 + c * 16;
    const int n0w = wave * 32;

    // ---- conv + silu ----
    {
        const int d8 = (tid & 63) * 8;
        ushort wl[32];
        *(uint4*)&wl[0]  = *(const uint4*)&cw[d8 * 4];
        *(uint4*)&wl[8]  = *(const uint4*)&cw[d8 * 4 + 8];
        *(uint4*)&wl[16] = *(const uint4*)&cw[d8 * 4 + 16];
        *(uint4*)&wl[24] = *(const uint4*)&cw[d8 * 4 + 24];
        ushort bl[8];
        *(uint4*)&bl[0] = *(const uint4*)&cb[d8];
        #pragma unroll
        for (int it = 0; it < 2; it++) {
            const int trow = it * 8 + wave;
            const int t = t0 + trow;
            const int l = t & 2047;
            float acc[8];
            #pragma unroll
            for (int j = 0; j < 8; j++) acc[j] = bf2f(bl[j]);
            #pragma unroll
            for (int k = 0; k < 4; k++) {
                const int ls = l - 3 + k;
                if (ls >= 0) {
                    ushort xl[8];
                    *(uint4*)&xl[0] = *(const uint4*)&xz[(size_t)(t - 3 + k) * 1024 + d8];
                    #pragma unroll
                    for (int j = 0; j < 8; j++) acc[j] += bf2f(xl[j]) * bf2f(wl[j * 4 + k]);
                }
            }
            ushort ol[8];
            #pragma unroll
            for (int j = 0; j < 8; j++) {
                const float s = acc[j] / (1.f + __expf(-acc[j]));
                ol[j] = f2bf(s);
            }
            *(uint4*)&yls[trow * 520 + d8] = *(uint4*)&ol[0];
        }
    }
    for (int e = tid; e < 768; e += 512)
        XD[e] = xdbl[(size_t)(t0 + (e / 48)) * 64 + (e % 48)];
    __syncthreads();

    // ---- scan pass 2: thread owns one d; y overwrites xi in LDS ----
    {
        const int d = tid;
        const uint4 w0 = *(const uint4*)&dtw[d * 16];
        const uint4 w1 = *(const uint4*)&dtw[d * 16 + 8];
        const float wd[16] = { bflo(w0.x), bfhi(w0.x), bflo(w0.y), bfhi(w0.y),
                               bflo(w0.z), bfhi(w0.z), bflo(w0.w), bfhi(w0.w),
                               bflo(w1.x), bfhi(w1.x), bflo(w1.y), bfhi(w1.y),
                               bflo(w1.z), bfhi(w1.z), bflo(w1.w), bfhi(w1.w) };
        const float dtbv = bf2f(dtb[d]);
        float A[16], h[16];
        #pragma unroll
        for (int n = 0; n < 16; n++) A[n] = -__expf(bf2f(Alog[d * 16 + n]));
        const int c32 = c >> 1;
        const size_t bh = ((size_t)(b * 64 + c32) * 16) * 512 + d;
        #pragma unroll
        for (int n = 0; n < 16; n++) h[n] = summh[bh + (size_t)n * 512];
        if (c & 1) {
            const float sdth = sdthalf[(size_t)(b * 64 + c32) * 512 + d];
            #pragma unroll
            for (int n = 0; n < 16; n++)
                h[n] = __expf(A[n] * sdth) * h[n] + hhalf[bh + (size_t)n * 512];
        }
        const float Dv = bf2f(Dssm[d]);
        for (int i = 0; i < 16; i++) {
            const int t = t0 + i;
            const float* Xr = &XD[i * 48];
            float s0 = dtbv, s1 = 0.f, s2 = 0.f, s3 = 0.f;
            #pragma unroll
            for (int k = 0; k < 16; k += 4) {
                s0 += Xr[k]     * wd[k];
                s1 += Xr[k + 1] * wd[k + 1];
                s2 += Xr[k + 2] * wd[k + 2];
                s3 += Xr[k + 3] * wd[k + 3];
            }
            const float s = (s0 + s1) + (s2 + s3);
            const float dtv = (s > 15.f) ? s : __logf(1.f + __expf(s));
            const float xiv = bf2f(yls[i * 520 + d]);
            const float dx = dtv * xiv;
            float yv0 = 0.f, yv1 = 0.f;
            #pragma unroll
            for (int n = 0; n < 16; n += 2) {
                const float da0 = __expf(dtv * A[n]);
                const float da1 = __expf(dtv * A[n + 1]);
                h[n]     = da0 * h[n]     + dx * Xr[16 + n];
                h[n + 1] = da1 * h[n + 1] + dx * Xr[17 + n];
                yv0 += h[n]     * Xr[32 + n];
                yv1 += h[n + 1] * Xr[33 + n];
            }
            float yv = yv0 + yv1;
            yv += xiv * Dv;
            const float zv = bf2f(xz[(size_t)t * 1024 + 512 + d]);
            yv *= zv / (1.f + __expf(-zv));
            yls[i * 520 + d] = f2bf(yv);   // in-place (same thread, same slot)
        }
    }
    __syncthreads();

    // ---- out_proj: M=16, N=256, K=512 from LDS y; B batch-preloaded 2x8 ----
    f32x4 accP[2];
    #pragma unroll
    for (int j = 0; j < 2; j++)
        #pragma unroll
        for (int r = 0; r < 4; r++) accP[j][r] = 0.f;
    {
        const ushort* bp0 = opw + (size_t)(n0w + lrow) * 512 + quad * 8;
        const ushort* bp1 = opw + (size_t)(n0w + 16 + lrow) * 512 + quad * 8;
        #pragma unroll
        for (int hh = 0; hh < 2; hh++) {
            bf16x8 B0[8], B1[8];
            #pragma unroll
            for (int s = 0; s < 8; s++) {
                B0[s] = *(const bf16x8*)(bp0 + hh * 256 + s * 32);
                B1[s] = *(const bf16x8*)(bp1 + hh * 256 + s * 32);
            }
            #pragma unroll
            for (int s = 0; s < 8; s++) {
                const bf16x8 afr = *(const bf16x8*)&yls[lrow * 520 + hh * 256 + s * 32 + quad * 8];
                accP[0] = __builtin_amdgcn_mfma_f32_16x16x32_bf16(afr, B0[s], accP[0], 0, 0, 0);
                accP[1] = __builtin_amdgcn_mfma_f32_16x16x32_bf16(afr, B1[s], accP[1], 0, 0, 0);
            }
        }
    }
    // epilogue + LN1 partials
    float vP[2][4];
    float ps[4], pq[4];
    #pragma unroll
    for (int r = 0; r < 4; r++) { ps[r] = 0.f; pq[r] = 0.f; }
    #pragma unroll
    for (int j = 0; j < 2; j++) {
        const int col = n0w + j * 16 + lrow;
        const float bv = bf2f(opb[col]);
        #pragma unroll
        for (int r = 0; r < 4; r++) {
            const int row = quad * 4 + r;
            float v = accP[j][r] + bv + bf2f(cx[(size_t)(t0 + row) * 256 + col]);
            vP[j][r] = v;
            ps[r] += v;
            pq[r] += v * v;
        }
    }
    #pragma unroll
    for (int r = 0; r < 4; r++) {
        #pragma unroll
        for (int o = 8; o > 0; o >>= 1) {
            ps[r] += __shfl_xor(ps[r], o);
            pq[r] += __shfl_xor(pq[r], o);
        }
        if (lrow == 0) {
            const int row = quad * 4 + r;
            redS[wave * 16 + row] = ps[r];
            redQ[wave * 16 + row] = pq[r];
        }
    }
    __syncthreads();

    // LN1 -> y1bs (bf16) + y1f in registers
    float y1f[2][4];
    #pragma unroll
    for (int r = 0; r < 4; r++) {
        const int row = quad * 4 + r;
        float S = 0.f, Q = 0.f;
        #pragma unroll
        for (int w = 0; w < 8; w++) { S += redS[w * 16 + row]; Q += redQ[w * 16 + row]; }
        const float mean = S * (1.f / 256.f);
        const float var  = Q * (1.f / 256.f) - mean * mean;
        const float rs   = rsqrtf(var + 1e-5f);
        #pragma unroll
        for (int j = 0; j < 2; j++) {
            const int col = n0w + j * 16 + lrow;
            const float o2 = (vP[j][r] - mean) * rs * bf2f(ln1g[col]) + bf2f(ln1b[col]);
            y1f[j][r] = o2;
            y1bs[row * 264 + col] = f2bf(o2);
        }
    }
    __syncthreads();

    // ---- fc1 (4 col-quarters) + fc2 partial-K accumulate; B batch-preloaded ----
    f32x4 acc2[2];
    #pragma unroll
    for (int j = 0; j < 2; j++)
        #pragma unroll
        for (int r = 0; r < 4; r++) acc2[j][r] = 0.f;

    for (int q = 0; q < 4; q++) {
        f32x4 a1[2];
        #pragma unroll
        for (int j = 0; j < 2; j++)
            #pragma unroll
            for (int r = 0; r < 4; r++) a1[j][r] = 0.f;
        {
            const ushort* bp0 = f1w + (size_t)(q * 256 + n0w + lrow) * 256 + quad * 8;
            const ushort* bp1 = f1w + (size_t)(q * 256 + n0w + 16 + lrow) * 256 + quad * 8;
            bf16x8 B0[8], B1[8];
            #pragma unroll
            for (int s = 0; s < 8; s++) {
                B0[s] = *(const bf16x8*)(bp0 + s * 32);
                B1[s] = *(const bf16x8*)(bp1 + s * 32);
            }
            #pragma unroll
            for (int s = 0; s < 8; s++) {
                const bf16x8 afr = *(const bf16x8*)&y1bs[lrow * 264 + s * 32 + quad * 8];
                a1[0] = __builtin_amdgcn_mfma_f32_16x16x32_bf16(afr, B0[s], a1[0], 0, 0, 0);
                a1[1] = __builtin_amdgcn_mfma_f32_16x16x32_bf16(afr, B1[s], a1[1], 0, 0, 0);
            }
        }
        #pragma unroll
        for (int j = 0; j < 2; j++) {
            const int qc = n0w + j * 16 + lrow;
            const float bv = bf2f(f1b[q * 256 + qc]);
            #pragma unroll
            for (int r = 0; r < 4; r++) {
                const int row = quad * 4 + r;
                f1q[row * 260 + qc] = f2bf(gelu_f(a1[j][r] + bv));
            }
        }
        __syncthreads();
        {
            const ushort* bp0 = f2w + (size_t)(n0w + lrow) * 1024 + q * 256 + quad * 8;
            const ushort* bp1 = f2w + (size_t)(n0w + 16 + lrow) * 1024 + q * 256 + quad * 8;
            bf16x8 B0[8], B1[8];
            #pragma unroll
            for (int s = 0; s < 8; s++) {
                B0[s] = *(const bf16x8*)(bp0 + s * 32);
                B1[s] = *(const bf16x8*)(bp1 + s * 32);
            }
            #pragma unroll
            for (int s = 0; s < 8; s++) {
                const bf16x8 afr = *(const bf16x8*)&f1q[lrow * 260 + s * 32 + quad * 8];
                acc2[0] = __builtin_amdgcn_mfma_f32_16x16x32_bf16(afr, B0[s], acc2[0], 0, 0, 0);
                acc2[1] = __builtin_amdgcn_mfma_f32_16x16x32_bf16(afr, B1[s], acc2[1], 0, 0, 0);
            }
        }
        __syncthreads();
    }

    // ---- fc2 epilogue: gelu + resid y1f, LN2, write d_out ----
    float v2[2][4];
    #pragma unroll
    for (int r = 0; r < 4; r++) { ps[r] = 0.f; pq[r] = 0.f; }
    #pragma unroll
    for (int j = 0; j < 2; j++) {
        const int col = n0w + j * 16 + lrow;
        const float bv = bf2f(f2b[col]);
        #pragma unroll
        for (int r = 0; r < 4; r++) {
            const float v = gelu_f(acc2[j][r] + bv) + y1f[j][r];
            v2[j][r] = v;
            ps[r] += v;
            pq[r] += v * v;
        }
    }
    #pragma unroll
    for (int r = 0; r < 4; r++) {
        #pragma unroll
        for (int o = 8; o > 0; o >>= 1) {
            ps[r] += __shfl_xor(ps[r], o);
            pq[r] += __shfl_xor(pq[r], o);
        }
        if (lrow == 0) {
            const int row = quad * 4 + r;
            redS[wave * 16 + row] = ps[r];
            redQ[wave * 16 + row] = pq[r];
        }
    }
    __syncthreads();

    const bool fl = sniff_inline(sniffx);
    #pragma unroll
    for (int r = 0; r < 4; r++) {
        const int row = quad * 4 + r;
        float S = 0.f, Q = 0.f;
        #pragma unroll
        for (int w = 0; w < 8; w++) { S += redS[w * 16 + row]; Q += redQ[w * 16 + row]; }
        const float mean = S * (1.f / 256.f);
        const float var  = Q * (1.f / 256.f) - mean * mean;
        const float rs   = rsqrtf(var + 1e-5f);
        #pragma unroll
        for (int j = 0; j < 2; j++) {
            const int col = n0w + j * 16 + lrow;
            const size_t off = (size_t)(t0 + row) * 256 + col;
            const float o2 = (v2[j][r] - mean) * rs * bf2f(ln2g[col]) + bf2f(ln2b[col]);
            if (fl) ((ushort*)dout)[off] = f2bf(o2);
            else    ((float*)dout)[off]  = o2;
        }
    }
}

// ---------------------------------------------------------------------------
extern "C" void kernel_launch(void* const* d_in, const int* in_sizes, int n_in,
                              void* d_out, int out_size, void* d_ws, size_t ws_size,
                              hipStream_t stream)
{
    char* ws = (char*)d_ws;
    ushort* canon = (ushort*)(ws + 256);

    static const int coff[20] = {
        0,        2097152,  2359296,  2360320,  2362368,
        2362880,  2387456,  2395648,  2396160,  2404352,
        2404864,  2535936,  2536192,  2536448,  2536704,
        2798848,  2799872,  3062016,  3062272,  3062528 };
    static const int ctot = 3062784;

    CanonArgs ca;
    for (int i = 0; i < 20; i++) { ca.src[i] = d_in[i]; ca.off[i] = coff[i]; }
    ca.total = ctot;

    const ushort* cx   = canon + coff[0];
    const ushort* cipw = canon + coff[1];
    const ushort* cipb = canon + coff[2];
    const ushort* ccw  = canon + coff[3];
    const ushort* ccb  = canon + coff[4];
    const ushort* cdtw = canon + coff[6];
    const ushort* cdtb = canon + coff[7];
    const ushort* calog= canon + coff[8];
    const ushort* cdssm= canon + coff[9];
    const ushort* copw = canon + coff[10];
    const ushort* copb = canon + coff[11];
    const ushort* cln1g= canon + coff[12];
    const ushort* cln1b= canon + coff[13];
    const ushort* cf1w = canon + coff[14];
    const ushort* cf1b = canon + coff[15];
    const ushort* cf2w = canon + coff[16];
    const ushort* cf2b = canon + coff[17];
    const ushort* cln2g= canon + coff[18];
    const ushort* cln2b= canon + coff[19];

    ushort* xpw_pad = (ushort*)(ws + 6291456);   // [64,512] bf16
    ushort* xz      = (ushort*)(ws + 8388608);   // [8192,1024] bf16, 16 MB
    float*  xdbl    = (float*)(ws + 25165824);   // [8192,64] f32, 2 MB
    float*  summh   = (float*)(ws + 27262976);   // [4,64,16,512] f32, 8 MB
    float*  hhalf   = (float*)(ws + 35651584);   // [4,64,16,512] f32, 8 MB
    float*  sdt32   = (float*)(ws + 44040192);   // [4,64,512] f32, 0.5 MB
    float*  sdthalf = (float*)(ws + 44564480);   // [4,64,512] f32, 0.5 MB
    const ushort* sx = (const ushort*)d_in[0];

    // 1. canon + xpw padding
    canon_k<<<(ctot + 8192 + 255) / 256, 256, 0, stream>>>(ca, canon, xpw_pad, sx);
    // 2. in_proj: xz = x @ ipw^T + ipb
    gemm_bt<128, 128><<<dim3(64, 8), 256, 0, stream>>>(cx, cipw, cipb, xz, 1024, 256);
    // 3. conv + silu + xdbl + scan1 (fused, 32-token chunks, half-states too)
    convscan1_k<<<dim3(64, 4), 512, 0, stream>>>(
        xz, ccw, ccb, xpw_pad, cdtw, cdtb, calog, xdbl, summh, sdt32, hhalf, sdthalf);
    // 4. combine (32-chunk boundary states, decay recomputed from sdt)
    combine_k<<<256, 128, 0, stream>>>(summh, sdt32, calog);
    // 5. tail: scan2 (16-token chunks, bridged) + out_proj + LN1 + FFN + LN2
    tail_k<<<dim3(128, 4), 512, 0, stream>>>(
        xz, ccw, ccb, xdbl, cdtw, cdtb, calog, summh, hhalf, sdthalf, cdssm, cx,
        copw, copb, cln1g, cln1b, cf1w, cf1b, cf2w, cf2b, cln2g, cln2b,
        d_out, sx);
}